// Round 8
// baseline (58.753 us; speedup 1.0000x reference)
//
#include <hip/hip_runtime.h>
#include <math.h>

#define B_ 16
#define L_ 1024
#define IMG 224
#define PIX (IMG*IMG)        /* 50176 */

/* ws layout: GPMIN[32], GPMAX[32], then g[B][224][224] */
#define OFF_GPMIN 0
#define OFF_GPMAX 32
#define OFF_G     64

__device__ __forceinline__ float cclip(float xn) {
    return fminf(fmaxf(xn, -1.0f + 1e-6f), 1.0f - 1e-6f);
}
__device__ __forceinline__ int bucketf(float c) {
    int k = (int)((c + 1.0f) * 512.0f);
    return min(1023, max(0, k));
}

template <int NTHR>
__device__ __forceinline__ void block_minmax_share(float mn, float mx, float* red) {
    #pragma unroll
    for (int off = 32; off > 0; off >>= 1) {
        mn = fminf(mn, __shfl_down(mn, off));
        mx = fmaxf(mx, __shfl_down(mx, off));
    }
    const int lane = threadIdx.x & 63;
    const int wave = threadIdx.x >> 6;
    if (lane == 0) { red[2 + wave*2] = mn; red[3 + wave*2] = mx; }
    __syncthreads();
    if (threadIdx.x == 0) {
        #pragma unroll
        for (int w = 1; w < NTHR/64; ++w) {
            mn = fminf(mn, red[2 + w*2]);
            mx = fmaxf(mx, red[3 + w*2]);
        }
        red[0] = mn; red[1] = mx;
    }
    __syncthreads();
}

/* per-d (d = lane&7, preserved by xor 8/16/32) block reduction of (mn,mx);
   results land in outmn[8], outmx[8]. scratch: 256 floats. */
__device__ __forceinline__ void perd_minmax(float mn, float mx,
                                            float* scratch,
                                            float* outmn, float* outmx) {
    #pragma unroll
    for (int o = 8; o <= 32; o <<= 1) {
        mn = fminf(mn, __shfl_xor(mn, o));
        mx = fmaxf(mx, __shfl_xor(mx, o));
    }
    int lane = threadIdx.x & 63, w = threadIdx.x >> 6;
    if (lane < 8) { scratch[(w*8 + lane)*2] = mn; scratch[(w*8 + lane)*2 + 1] = mx; }
    __syncthreads();
    if (threadIdx.x < 8) {
        float m = 1e30f, M = -1e30f;
        #pragma unroll
        for (int ww = 0; ww < 16; ++ww) {
            m = fminf(m, scratch[(ww*8 + threadIdx.x)*2]);
            M = fmaxf(M, scratch[(ww*8 + threadIdx.x)*2 + 1]);
        }
        outmn[threadIdx.x] = m; outmx[threadIdx.x] = M;
    }
    __syncthreads();
}

/* K1: 32 blocks = (b, half) x 1024 threads. Per block:
   (1) redundant global x min/max  (2) all 8 per-d bucket counting-sorts of
   batch b concurrently in LDS  (3) analytic pair min/max per d (span search
   around -c_i; every eval is an exact pair, extras harmless)  (4) a[d], bias
   (5) P/Q sample matrices overlaying the dead sort buffer — STRIDED loop so
       all 224x8 entries are covered by 1024 threads (R6/R7 bug: `if t<1792`)
   (6) register-tiled resize of this block's 112 rows + g min/max partial. */
__global__ __launch_bounds__(1024) void k_bd_fused(const float* __restrict__ x,
                                                   float* __restrict__ wsf) {
    __shared__ float red[34];
    __shared__ __align__(16) float corig[L_*8];          /* [l][d]    32 KB */
    __shared__ __align__(16) float arr[8][L_];           /* sorted/d  32 KB */
    __shared__ __align__(16) unsigned char ubuf[8*1024*4 + 8*1026*2]; /* 48 KB */
    __shared__ float pdred[256];
    __shared__ float cdmn[8], cdmx[8], aLds[8], termLds[8];
    __shared__ float biasLds;

    int* cnt            = (int*)ubuf;                    /* [8][1024] ints  */
    unsigned short* prf = (unsigned short*)(ubuf + 32768); /* [8][1026] u16 */
    float* PQ           = (float*)ubuf;                  /* overlay, phase 5+ */

    const int blk = blockIdx.x;
    const int b = blk >> 1, h = blk & 1;
    const int t = threadIdx.x;
    const int d = t & 7;

#define CNT(dd,k)  cnt[(dd)*1024 + (k)]
#define PREF(dd,k) prf[(dd)*1026 + (k)]

    /* (1) global x min/max, redundant per block (identical results) */
    {
        float mn = 1e30f, mx = -1e30f;
        const float4* xv = (const float4*)x;
        #pragma unroll 4
        for (int i = t; i < 32768; i += 1024) {
            float4 v = xv[i];
            mn = fminf(mn, fminf(fminf(v.x, v.y), fminf(v.z, v.w)));
            mx = fmaxf(mx, fmaxf(fmaxf(v.x, v.y), fmaxf(v.z, v.w)));
        }
        block_minmax_share<1024>(mn, mx, red);
    }
    float lo = red[0], hi = red[1], r = hi - lo, sc, sh;
    if (r < 1e-8f) { sc = 0.0f; sh = -1.0f; }
    else           { sc = 2.0f / (r + 1e-8f); sh = -lo*sc - 1.0f; }

    /* (2) load batch rows; thread owns 8 elems of one d; zero counts */
    float c[8];
    {
        const float* xb = x + (size_t)b*8192;
        float cmn = 1e30f, cmx = -1e30f;
        #pragma unroll
        for (int k = 0; k < 8; ++k) {
            int e = t + k*1024;              /* e = l*8 + d, d = t&7 const */
            float cv = cclip(xb[e]*sc + sh);
            c[k] = cv;
            corig[e] = cv;
            cnt[e] = 0;                      /* zero count region */
            cmn = fminf(cmn, cv); cmx = fmaxf(cmx, cv);
        }
        __syncthreads();
        perd_minmax(cmn, cmx, pdred, cdmn, cdmx);
    }

    /* count */
    #pragma unroll
    for (int k = 0; k < 8; ++k)
        atomicAdd(&CNT(d, bucketf(c[k])), 1);
    __syncthreads();

    /* per-d exclusive prefix: wave dd scans its 1024 buckets */
    {
        int w = t >> 6, lane = t & 63;
        if (w < 8) {
            int s = 0;
            #pragma unroll
            for (int e = 0; e < 16; ++e) s += CNT(w, lane*16 + e);
            int v = s;
            #pragma unroll
            for (int o = 1; o < 64; o <<= 1) {
                int u = __shfl_up(v, o);
                if (lane >= o) v += u;
            }
            int run = v - s;
            #pragma unroll
            for (int e = 0; e < 16; ++e) {
                PREF(w, lane*16 + e) = (unsigned short)run;
                run += CNT(w, lane*16 + e);
            }
            if (lane == 63) PREF(w, 1024) = (unsigned short)run;
        }
    }
    __syncthreads();
    /* cursors = pref (copy into cnt region) */
    #pragma unroll
    for (int k = 0; k < 8; ++k) {
        int idx = t + k*1024;
        cnt[idx] = (int)PREF(idx >> 10, idx & 1023);
    }
    __syncthreads();
    /* scatter */
    #pragma unroll
    for (int k = 0; k < 8; ++k) {
        int p = atomicAdd(&CNT(d, bucketf(c[k])), 1);
        arr[d][p] = c[k];
    }
    __syncthreads();

    /* (3) pair-min via neighbor span of -c_i */
    {
        float rowmin = 1e30f;
        const float* arrd = &arr[d][0];
        #pragma unroll
        for (int k = 0; k < 8; ++k) {
            float ci = c[k];
            float si = sqrtf(fmaxf(1.0f - ci*ci, 0.0f));
            int kt = bucketf(-ci);
            int lo_p = (int)PREF(d, kt), hi_p = (int)PREF(d, kt + 1);
            int start = lo_p, end = hi_p;
            if (lo_p > 0)    start = (int)PREF(d, bucketf(arrd[lo_p - 1]));
            if (hi_p < L_)   end   = (int)PREF(d, bucketf(arrd[hi_p]) + 1);
            for (int p = start; p < end; ++p) {
                float cj = arrd[p];
                float sj = sqrtf(fmaxf(1.0f - cj*cj, 0.0f));
                rowmin = fminf(rowmin, ci*cj - si*sj);
            }
        }
        __syncthreads();
        perd_minmax(rowmin, -1e30f, pdred, aLds /*tmp plo*/, termLds /*unused*/);
    }
    /* (4) a[d], bias (aLds currently holds plo per d) */
    if (t < 8) {
        float plo = aLds[t];
        float cm = cdmn[t], cM = cdmx[t];
        float phi = fmaxf(2.0f*cm*cm - 1.0f, 2.0f*cM*cM - 1.0f);
        float rr  = phi - plo;
        float inv = (rr < 1e-8f) ? 0.0f : 1.0f / (rr + 1e-8f);
        aLds[t]    = inv * 0.125f;
        termLds[t] = plo * inv * 0.125f;
    }
    __syncthreads();
    if (t == 0) {
        float s = 0.f;
        #pragma unroll
        for (int dd = 0; dd < 8; ++dd) s += termLds[dd];
        biasLds = s;
    }
    __syncthreads();

    /* (5) P/Q sample matrices overlaying ubuf (cnt/prf dead).
       P[o][k] = [a_d*cy_d, a_d*sy_d], Q[o][k] = [cx_d, -sx_d];
       row stride 20 floats (80 B). STRIDED loop: 1792 entries, 1024 thr. */
    for (int e = t; e < 1792; e += 1024) {
        int o = e >> 3, dd = e & 7;
        const float SC = 1024.0f / 224.0f;
        float syf = (o + 0.5f)*SC - 0.5f;
        int i0 = (int)floorf(syf);
        i0 = max(0, min(i0, L_ - 2));
        float f = syf - (float)i0;
        float ca = corig[i0*8 + dd], cb = corig[(i0+1)*8 + dd];
        float sa = sqrtf(fmaxf(1.0f - ca*ca, 0.0f));
        float sb = sqrtf(fmaxf(1.0f - cb*cb, 0.0f));
        float hc = ca + f*(cb - ca);
        float hs = sa + f*(sb - sa);
        float ad = aLds[dd];
        PQ[o*20 + dd]            = ad * hc;
        PQ[o*20 + 8 + dd]        = ad * hs;
        PQ[4480 + o*20 + dd]     = hc;
        PQ[4480 + o*20 + 8 + dd] = -hs;
    }
    __syncthreads();

    /* (6) resize this half: 112 oy x 224 ox. thread = (ty 16, tx 64);
       tx<56 active, each owns ox = tx + 56j (j<4), X hoisted to regs. */
    {
        int ty = t >> 6, tx = t & 63;
        bool act = (tx < 56);
        int txc = act ? tx : 0;
        float4 Xq[4][4];
        #pragma unroll
        for (int j = 0; j < 4; ++j) {
            const float4* qv = (const float4*)&PQ[4480 + (txc + 56*j)*20];
            Xq[j][0] = qv[0]; Xq[j][1] = qv[1]; Xq[j][2] = qv[2]; Xq[j][3] = qv[3];
        }
        float bias = biasLds;
        float mn = 1e30f, mx = -1e30f;
        #pragma unroll
        for (int rr = 0; rr < 7; ++rr) {
            int oy = h*112 + ty*7 + rr;
            const float4* yv = (const float4*)&PQ[oy*20];
            float4 Y0 = yv[0], Y1 = yv[1], Y2 = yv[2], Y3 = yv[3];
            #pragma unroll
            for (int j = 0; j < 4; ++j) {
                float acc;
                acc  = Y0.x*Xq[j][0].x + Y0.y*Xq[j][0].y + Y0.z*Xq[j][0].z + Y0.w*Xq[j][0].w;
                acc += Y1.x*Xq[j][1].x + Y1.y*Xq[j][1].y + Y1.z*Xq[j][1].z + Y1.w*Xq[j][1].w;
                acc += Y2.x*Xq[j][2].x + Y2.y*Xq[j][2].y + Y2.z*Xq[j][2].z + Y2.w*Xq[j][2].w;
                acc += Y3.x*Xq[j][3].x + Y3.y*Xq[j][3].y + Y3.z*Xq[j][3].z + Y3.w*Xq[j][3].w;
                float g = acc - bias;
                if (act) {
                    wsf[OFF_G + (size_t)b*PIX + (size_t)oy*IMG + tx + 56*j] = g;
                    mn = fminf(mn, g);
                    mx = fmaxf(mx, g);
                }
            }
        }
        block_minmax_share<1024>(mn, mx, red);
        if (t == 0) {
            wsf[OFF_GPMIN + blk] = red[0];
            wsf[OFF_GPMAX + blk] = red[1];
        }
    }
#undef CNT
#undef PREF
}

/* K2: reduce 32 g-partials (redundant per block), normalize, x3 write */
__global__ __launch_bounds__(256) void k_out(const float* __restrict__ wsf,
                                             float* __restrict__ out) {
    __shared__ float red[16];
    int t = threadIdx.x;
    float pmn = (t < 32) ? wsf[OFF_GPMIN + t] :  1e30f;
    float pmx = (t < 32) ? wsf[OFF_GPMAX + t] : -1e30f;
    block_minmax_share<256>(pmn, pmx, red);
    float gmin = red[0];
    float scale = 1.0f / ((red[1] - gmin) + 1e-6f);
    int idx = blockIdx.x*256 + t;                /* [0, 200704) float4 */
    float4 gv = ((const float4*)(wsf + OFF_G))[idx];
    float4 v;
    v.x = (gv.x - gmin)*scale;
    v.y = (gv.y - gmin)*scale;
    v.z = (gv.z - gmin)*scale;
    v.w = (gv.w - gmin)*scale;
    int b   = idx / (PIX/4);
    int rem = idx - b*(PIX/4);
    float4* ob = (float4*)(out + (size_t)b*3*PIX) + rem;
    ob[0]         = v;
    ob[PIX/4]     = v;
    ob[2*(PIX/4)] = v;
}

extern "C" void kernel_launch(void* const* d_in, const int* in_sizes, int n_in,
                              void* d_out, int out_size, void* d_ws, size_t ws_size,
                              hipStream_t stream) {
    const float* x = (const float*)d_in[0];
    float* out     = (float*)d_out;
    float* wsf     = (float*)d_ws;

    k_bd_fused<<<32,             1024, 0, stream>>>(x, wsf);
    k_out     <<<(B_*PIX/4)/256, 256,  0, stream>>>(wsf, out);
}

// Round 9
// 28.046 us; speedup vs baseline: 2.0949x; 2.0949x over previous
//
#include <hip/hip_runtime.h>
#include <math.h>

#define B_ 16
#define L_ 1024
#define IMG 224
#define PIX (IMG*IMG)        /* 50176 */
#define NBD 128

/* ---- workspace (float) layout — plain stores only, no atomics, no init ----
   OFF_A    : a[128]    = inv/8 per (b,d)
   OFF_TERM : term[128] = lo*inv/8 per (b,d)
   OFF_GPMIN: g min partials[512]   OFF_GPMAX: g max partials[512]
   OFF_T    : tbl[B][224][16]  (lerped c[0..7], s[0..7] at sample positions)
   OFF_G    : g[B][224][224]
*/
#define OFF_A     0
#define OFF_TERM  128
#define OFF_GPMIN 256
#define OFF_GPMAX 768
#define OFF_T     1280                 /* 57344 floats */
#define OFF_G     58624                /* 802816 floats */

/* pad-17 bucket layout: bucket k -> slot (k>>4)*17 + (k&15).
   scan reads stride-17 (all banks, gcd(17,32)=1); adjacent buckets ->
   adjacent banks for the data-dependent count atomics. */
#define CPAD(k) ((((k) >> 4) * 17) + ((k) & 15))

__device__ __forceinline__ float cclip(float xn) {
    return fminf(fmaxf(xn, -1.0f + 1e-6f), 1.0f - 1e-6f);
}
__device__ __forceinline__ int bucketf(float c) {
    int k = (int)((c + 1.0f) * 512.0f);
    return min(1023, max(0, k));
}

template <int NTHR>
__device__ __forceinline__ void block_minmax_share(float mn, float mx, float* red) {
    #pragma unroll
    for (int off = 32; off > 0; off >>= 1) {
        mn = fminf(mn, __shfl_down(mn, off));
        mx = fmaxf(mx, __shfl_down(mx, off));
    }
    const int lane = threadIdx.x & 63;
    const int wave = threadIdx.x >> 6;
    if (lane == 0) { red[2 + wave*2] = mn; red[3 + wave*2] = mx; }
    __syncthreads();
    if (threadIdx.x == 0) {
        #pragma unroll
        for (int w = 1; w < NTHR/64; ++w) {
            mn = fminf(mn, red[2 + w*2]);
            mx = fmaxf(mx, red[3 + w*2]);
        }
        red[0] = mn; red[1] = mx;
    }
    __syncthreads();
}

/* K1: one block per (b,d), 1024 threads (1 row each).
   (a) redundant global x min/max (x is L2-resident; identical per block)
   (b) bucket counting-sort (pad-17, conflict-free scan)
   (c) analytic pair min/max:
         max = max(2*cmin^2-1, 2*cmax^2-1)
         min = min over i of exact cos at the c-neighbors of -c_i
   (d) a[bd], term[bd]; (e) d-slice of the (c,s) sample table. */
__global__ __launch_bounds__(1024) void k_bd(const float* __restrict__ x,
                                             float* __restrict__ wsf) {
    __shared__ float red[36];
    __shared__ float corig[L_];
    __shared__ float arr[L_];
    __shared__ int   cnt[1090];        /* counts, then scatter cursors */
    __shared__ int   pref[1090];
    const int bd = blockIdx.x;
    const int b = bd >> 3, d = bd & 7;
    const int t = threadIdx.x;

    /* (a) global x min/max */
    {
        float mn = 1e30f, mx = -1e30f;
        const float4* xv = (const float4*)x;
        #pragma unroll 4
        for (int i = t; i < 32768; i += 1024) {
            float4 v = xv[i];
            mn = fminf(mn, fminf(fminf(v.x, v.y), fminf(v.z, v.w)));
            mx = fmaxf(mx, fmaxf(fmaxf(v.x, v.y), fmaxf(v.z, v.w)));
        }
        block_minmax_share<1024>(mn, mx, red);
    }
    float lo = red[0], hi = red[1], r = hi - lo, sc, sh;
    if (r < 1e-8f) { sc = 0.0f; sh = -1.0f; }
    else           { sc = 2.0f / (r + 1e-8f); sh = -lo*sc - 1.0f; }

    /* (b) load row (1/thread), zero counts */
    cnt[t] = 0;
    if (t < 66) cnt[1024 + t] = 0;
    float c = cclip(x[((size_t)(b*L_ + t))*8 + d]*sc + sh);
    corig[t] = c;
    block_minmax_share<1024>(c, c, red);      /* also orders cnt/corig */
    float cMin = red[0], cMax = red[1];

    /* count */
    atomicAdd(&cnt[CPAD(bucketf(c))], 1);
    __syncthreads();

    /* exclusive prefix over 1024 buckets: wave 0, 16 buckets/lane,
       pad-17 -> conflict-free reads/writes */
    if (t < 64) {
        int s = 0;
        #pragma unroll
        for (int e = 0; e < 16; ++e) s += cnt[t*17 + e];
        int v = s;
        #pragma unroll
        for (int o = 1; o < 64; o <<= 1) {
            int u = __shfl_up(v, o);
            if (t >= o) v += u;
        }
        int run = v - s;                      /* exclusive chunk prefix */
        #pragma unroll
        for (int e = 0; e < 16; ++e) { pref[t*17 + e] = run; run += cnt[t*17 + e]; }
        if (t == 63) pref[CPAD(1024)] = run;
    }
    __syncthreads();
    cnt[CPAD(t)] = pref[CPAD(t)];             /* cursors, bucket t */
    __syncthreads();
    /* scatter */
    {
        int p = atomicAdd(&cnt[CPAD(bucketf(c))], 1);
        arr[p] = c;
    }
    __syncthreads();

    /* (c) pair-min via neighbor span of -c_i (1 target/thread) */
    float rowmin = 1e30f;
    {
        float ci = c;
        float si = sqrtf(fmaxf(1.0f - ci*ci, 0.0f));
        int kt = bucketf(-ci);
        int lo_p = pref[CPAD(kt)], hi_p = pref[CPAD(kt + 1)];
        int start = lo_p, end = hi_p;
        if (lo_p > 0)   start = pref[CPAD(bucketf(arr[lo_p - 1]))];
        if (hi_p < L_)  end   = pref[CPAD(bucketf(arr[hi_p]) + 1)];
        for (int p = start; p < end; ++p) {
            float cj = arr[p];
            float sj = sqrtf(fmaxf(1.0f - cj*cj, 0.0f));
            rowmin = fminf(rowmin, ci*cj - si*sj);
        }
    }
    block_minmax_share<1024>(rowmin, -1e30f, red);
    if (t == 0) {
        float plo = red[0];
        float phi = fmaxf(2.0f*cMin*cMin - 1.0f, 2.0f*cMax*cMax - 1.0f);
        float rr  = phi - plo;
        float inv = (rr < 1e-8f) ? 0.0f : 1.0f / (rr + 1e-8f);
        wsf[OFF_A + bd]    = inv * 0.125f;
        wsf[OFF_TERM + bd] = plo * inv * 0.125f;
    }

    /* (e) sample table d-slice: lerped (c,s) at 224 half-pixel positions */
    if (t < IMG) {
        const float SC = 1024.0f / 224.0f;
        float syf = (t + 0.5f)*SC - 0.5f;
        int i0 = (int)floorf(syf);
        i0 = max(0, min(i0, L_ - 2));
        float f = syf - (float)i0;
        float ca = corig[i0], cb = corig[i0 + 1];
        float sa = sqrtf(fmaxf(1.0f - ca*ca, 0.0f));
        float sb = sqrtf(fmaxf(1.0f - cb*cb, 0.0f));
        size_t base = OFF_T + ((size_t)(b*IMG + t))*16;
        wsf[base + d]     = ca + f*(cb - ca);
        wsf[base + 8 + d] = sa + f*(sb - sa);
    }
}

/* K2: resize. 512 blocks = 16 b x 32 strips of 7 rows; thread = ox.
   x-side (c,s) coalesced from table, y-side via 112-float LDS strip.
   g min/max per block -> plain-store partials. */
__global__ __launch_bounds__(256) void k_resize(float* __restrict__ wsf) {
    __shared__ float lds_y[112];
    __shared__ float red[16];
    int b     = blockIdx.x >> 5;
    int strip = blockIdx.x & 31;
    const float* tb = wsf + OFF_T + (size_t)b*IMG*16;
    int t = threadIdx.x;
    if (t < 112) lds_y[t] = tb[strip*112 + t];
    __syncthreads();
    int ox = min(t, IMG-1);
    bool active = (t < IMG);
    const float4* xt = (const float4*)(tb + (size_t)ox*16);
    float4 cx0 = xt[0], cx1 = xt[1], sx0 = xt[2], sx1 = xt[3];
    const float4* av = (const float4*)(wsf + OFF_A + b*8);
    float4 a0 = av[0], a1 = av[1];
    float bias = 0.f;
    #pragma unroll
    for (int dd = 0; dd < 8; ++dd) bias += wsf[OFF_TERM + b*8 + dd];
    float mn = 1e30f, mx = -1e30f;
    #pragma unroll
    for (int rr = 0; rr < 7; ++rr) {
        const float* Y = lds_y + rr*16;
        float acc;
        acc  = (a0.x*Y[0])*cx0.x - (a0.x*Y[ 8])*sx0.x;
        acc += (a0.y*Y[1])*cx0.y - (a0.y*Y[ 9])*sx0.y;
        acc += (a0.z*Y[2])*cx0.z - (a0.z*Y[10])*sx0.z;
        acc += (a0.w*Y[3])*cx0.w - (a0.w*Y[11])*sx0.w;
        acc += (a1.x*Y[4])*cx1.x - (a1.x*Y[12])*sx1.x;
        acc += (a1.y*Y[5])*cx1.y - (a1.y*Y[13])*sx1.y;
        acc += (a1.z*Y[6])*cx1.z - (a1.z*Y[14])*sx1.z;
        acc += (a1.w*Y[7])*cx1.w - (a1.w*Y[15])*sx1.w;
        float g = acc - bias;
        if (active) {
            int oy = strip*7 + rr;
            wsf[OFF_G + ((size_t)(b*IMG + oy))*IMG + ox] = g;
            mn = fminf(mn, g);
            mx = fmaxf(mx, g);
        }
    }
    block_minmax_share<256>(mn, mx, red);
    if (t == 0) {
        wsf[OFF_GPMIN + blockIdx.x] = red[0];
        wsf[OFF_GPMAX + blockIdx.x] = red[1];
    }
}

/* K3: reduce 512 g-partials per block, normalize, 3-channel float4 write */
__global__ __launch_bounds__(256) void k_out(const float* __restrict__ wsf,
                                             float* __restrict__ out) {
    __shared__ float red[16];
    int t = threadIdx.x;
    float pmn = fminf(wsf[OFF_GPMIN + t], wsf[OFF_GPMIN + t + 256]);
    float pmx = fmaxf(wsf[OFF_GPMAX + t], wsf[OFF_GPMAX + t + 256]);
    block_minmax_share<256>(pmn, pmx, red);
    float gmin = red[0];
    float scale = 1.0f / ((red[1] - gmin) + 1e-6f);
    int idx = blockIdx.x*256 + t;                /* [0, 200704) float4 groups */
    float4 gv = ((const float4*)(wsf + OFF_G))[idx];
    float4 v;
    v.x = (gv.x - gmin)*scale;
    v.y = (gv.y - gmin)*scale;
    v.z = (gv.z - gmin)*scale;
    v.w = (gv.w - gmin)*scale;
    int b   = idx / (PIX/4);
    int rem = idx - b*(PIX/4);
    float4* ob = (float4*)(out + (size_t)b*3*PIX) + rem;
    ob[0]         = v;
    ob[PIX/4]     = v;
    ob[2*(PIX/4)] = v;
}

extern "C" void kernel_launch(void* const* d_in, const int* in_sizes, int n_in,
                              void* d_out, int out_size, void* d_ws, size_t ws_size,
                              hipStream_t stream) {
    const float* x = (const float*)d_in[0];
    float* out     = (float*)d_out;
    float* wsf     = (float*)d_ws;

    k_bd    <<<NBD,            1024, 0, stream>>>(x, wsf);
    k_resize<<<512,            256,  0, stream>>>(wsf);
    k_out   <<<(B_*PIX/4)/256, 256,  0, stream>>>(wsf, out);
}